// Round 2
// baseline (1136.569 us; speedup 1.0000x reference)
//
#include <hip/hip_runtime.h>
#include <hip/hip_bf16.h>

// Tree: B=512, A=4, D=6, N=1365, E=128. Level starts: {0,1,5,21,85,341}.
// One block per batch element (grid=512, 512 threads). Whole tree bottom-up in
// LDS; no workspace, no atomics, no memset -> pure function of d_in (replay-safe).
#define NTOK 1365
#define ED   128

constexpr int XSTR = 132;  // LDS row stride (floats): %4==0 for b128 align; 132%32=4 -> <=2-way conflict (free, m136)

// C[r][c] = sum_k X[r][k] * W[c][k]; W row-major [128][128] in global (wave-broadcast loads).
// 512 threads: rg=tid&15 (row group), cg=tid>>4 (0..31); cols c = cg + 32*j, j<4.
// rows r = rg + 16*i, i<RP. Internal __syncthreads() separates producer LDS writes from reads.
template<int RP, int NR>
__device__ __forceinline__ void gemm_tile(const float* __restrict__ Wg,
                                          const float* __restrict__ Xl,
                                          int rg, int cg, float acc[RP][4]) {
  #pragma unroll
  for (int i = 0; i < RP; i++)
    #pragma unroll
    for (int j = 0; j < 4; j++) acc[i][j] = 0.f;
  __syncthreads();
  #pragma unroll 2
  for (int k = 0; k < ED; k += 4) {
    float4 wv[4];
    #pragma unroll
    for (int j = 0; j < 4; j++)
      wv[j] = *(const float4*)(Wg + (cg + 32*j)*ED + k);  // 16 rg-lanes share addr -> broadcast
    #pragma unroll
    for (int i = 0; i < RP; i++) {
      const int r = rg + 16*i;
      if (NR >= 16 || r < NR) {
        float4 xv = *(const float4*)(Xl + r*XSTR + k);
        #pragma unroll
        for (int j = 0; j < 4; j++)
          acc[i][j] += xv.x*wv[j].x + xv.y*wv[j].y + xv.z*wv[j].z + xv.w*wv[j].w;
      }
    }
  }
}

__global__ __launch_bounds__(512, 4) void tree_kernel(
    const int* __restrict__ tokens, const float* __restrict__ emb,
    const float* __restrict__ WcW,  const float* __restrict__ Wcb,
    const float* __restrict__ WsW,  const float* __restrict__ Wsb,
    float* __restrict__ out) {

  __shared__ float Xb[32 * XSTR];   // 16896 B: gather staging / h writeback / final reduce
  __shared__ float A4[64 * XSTR];   // 33792 B: level-4 child-sums -> projected aggregates
  __shared__ float S3[16 * XSTR];   // 8448 B
  __shared__ float S2[4 * XSTR];    // 2112 B
  __shared__ float S1[XSTR];        // 528 B
  __shared__ float H1[ED];          // 512 B: running sum of the 4 level-1 h vectors
  __shared__ float biasC[ED];       // Wc_b
  __shared__ float biasS4[ED];      // 4*Ws_b
  // total 63312 B < 64 KiB -> 2 blocks/CU (16 waves/CU, 4/SIMD)

  const int tid = threadIdx.x;
  const int b   = blockIdx.x;
  const int rg  = tid & 15;
  const int cg  = tid >> 4;       // 0..31
  const long tokbase = (long)b * NTOK;

  if (tid < ED) { biasC[tid] = Wcb[tid]; biasS4[tid] = 4.0f * Wsb[tid]; H1[tid] = 0.f; }

  float pmax[4];
  #pragma unroll
  for (int j = 0; j < 4; j++) pmax[j] = 0.f;  // relu floor

  for (int c1 = 0; c1 < 4; c1++) {
    // ===== Level 5 (leaves): 256 nodes, 8 chunks of 32. h = e. Quad-sum -> A4 =====
    for (int ch = 0; ch < 8; ch++) {
      {
        const int r = tid >> 4, p = tid & 15;
        const int tok = tokens[tokbase + 341 + c1*256 + ch*32 + r];
        const float4* src = (const float4*)(emb + (long)tok * ED);
        float4 v0 = src[p], v1 = src[p + 16];
        float* dst = Xb + r*XSTR + 4*p;
        *(float4*)(dst)      = v0;
        *(float4*)(dst + 64) = v1;
      }
      float acc[2][4];
      gemm_tile<2,32>(WcW, Xb, rg, cg, acc);
      __syncthreads();
      #pragma unroll
      for (int i = 0; i < 2; i++) {
        const int r = rg + 16*i;
        #pragma unroll
        for (int j = 0; j < 4; j++) {
          const int c = cg + 32*j;
          float e = acc[i][j] + biasC[c];
          pmax[j] = fmaxf(pmax[j], e);
          Xb[r*XSTR + c] = e;
        }
      }
      __syncthreads();
      {
        const int col = tid & 127, ph = tid >> 7;  // ph 0..3
        #pragma unroll
        for (int q = 0; q < 2; q++) {
          const int pl = ph + 4*q;  // 8 parents/chunk, each (pl,col) written once
          A4[(ch*8 + pl)*XSTR + col] =
              Xb[(4*pl+0)*XSTR + col] + Xb[(4*pl+1)*XSTR + col]
            + Xb[(4*pl+2)*XSTR + col] + Xb[(4*pl+3)*XSTR + col];
        }
      }
      __syncthreads();
    }

    // ===== A4 <- A4 @ Ws^T + 4*b_s (M=64, in-place) =====
    {
      float acc[4][4];
      gemm_tile<4,64>(WsW, A4, rg, cg, acc);
      __syncthreads();
      #pragma unroll
      for (int i = 0; i < 4; i++)
        #pragma unroll
        for (int j = 0; j < 4; j++)
          A4[(rg + 16*i)*XSTR + cg + 32*j] = acc[i][j] + biasS4[cg + 32*j];
      __syncthreads();
    }

    // ===== Level 4: 64 nodes, 2 chunks of 32. h = e + A4. Quad-sum -> S3 =====
    for (int ch = 0; ch < 2; ch++) {
      {
        const int r = tid >> 4, p = tid & 15;
        const int tok = tokens[tokbase + 85 + c1*64 + ch*32 + r];
        const float4* src = (const float4*)(emb + (long)tok * ED);
        float4 v0 = src[p], v1 = src[p + 16];
        float* dst = Xb + r*XSTR + 4*p;
        *(float4*)(dst)      = v0;
        *(float4*)(dst + 64) = v1;
      }
      float acc[2][4];
      gemm_tile<2,32>(WcW, Xb, rg, cg, acc);
      __syncthreads();
      #pragma unroll
      for (int i = 0; i < 2; i++) {
        const int r = rg + 16*i;
        #pragma unroll
        for (int j = 0; j < 4; j++) {
          const int c = cg + 32*j;
          float h = acc[i][j] + biasC[c] + A4[(ch*32 + r)*XSTR + c];
          pmax[j] = fmaxf(pmax[j], h);
          Xb[r*XSTR + c] = h;
        }
      }
      __syncthreads();
      {
        const int col = tid & 127, ph = tid >> 7;
        #pragma unroll
        for (int q = 0; q < 2; q++) {
          const int pl = ph + 4*q;
          S3[(ch*8 + pl)*XSTR + col] =
              Xb[(4*pl+0)*XSTR + col] + Xb[(4*pl+1)*XSTR + col]
            + Xb[(4*pl+2)*XSTR + col] + Xb[(4*pl+3)*XSTR + col];
        }
      }
      __syncthreads();
    }

    // ===== S3 <- S3 @ Ws^T + 4*b_s (M=16) =====
    {
      float acc[1][4];
      gemm_tile<1,16>(WsW, S3, rg, cg, acc);
      __syncthreads();
      #pragma unroll
      for (int j = 0; j < 4; j++)
        S3[rg*XSTR + cg + 32*j] = acc[0][j] + biasS4[cg + 32*j];
      __syncthreads();
    }

    // ===== Level 3: 16 nodes. h = e + S3. Quad-sum -> S2 =====
    {
      {
        const int r = tid >> 5, p = tid & 31;
        const int tok = tokens[tokbase + 21 + c1*16 + r];
        *(float4*)(Xb + r*XSTR + 4*p) = ((const float4*)(emb + (long)tok * ED))[p];
      }
      float acc[1][4];
      gemm_tile<1,16>(WcW, Xb, rg, cg, acc);
      __syncthreads();
      #pragma unroll
      for (int j = 0; j < 4; j++) {
        const int c = cg + 32*j;
        float h = acc[0][j] + biasC[c] + S3[rg*XSTR + c];
        pmax[j] = fmaxf(pmax[j], h);
        Xb[rg*XSTR + c] = h;
      }
      __syncthreads();
      {
        const int col = tid & 127, ph = tid >> 7;  // 4 parents, each once
        S2[ph*XSTR + col] =
            Xb[(4*ph+0)*XSTR + col] + Xb[(4*ph+1)*XSTR + col]
          + Xb[(4*ph+2)*XSTR + col] + Xb[(4*ph+3)*XSTR + col];
      }
      __syncthreads();
    }

    // ===== S2 <- S2 @ Ws^T + 4*b_s (M=4) =====
    {
      float acc[1][4];
      gemm_tile<1,4>(WsW, S2, rg, cg, acc);
      __syncthreads();
      if (rg < 4) {
        #pragma unroll
        for (int j = 0; j < 4; j++)
          S2[rg*XSTR + cg + 32*j] = acc[0][j] + biasS4[cg + 32*j];
      }
      __syncthreads();
    }

    // ===== Level 2: 4 nodes. h = e + S2. Sum -> S1 =====
    {
      if (tid < 128) {
        const int r = tid >> 5, p = tid & 31;
        const int tok = tokens[tokbase + 5 + c1*4 + r];
        *(float4*)(Xb + r*XSTR + 4*p) = ((const float4*)(emb + (long)tok * ED))[p];
      }
      float acc[1][4];
      gemm_tile<1,4>(WcW, Xb, rg, cg, acc);
      __syncthreads();
      if (rg < 4) {
        #pragma unroll
        for (int j = 0; j < 4; j++) {
          const int c = cg + 32*j;
          float h = acc[0][j] + biasC[c] + S2[rg*XSTR + c];
          pmax[j] = fmaxf(pmax[j], h);
          Xb[rg*XSTR + c] = h;
        }
      }
      __syncthreads();
      if (tid < 128)
        S1[tid] = Xb[tid] + Xb[XSTR + tid] + Xb[2*XSTR + tid] + Xb[3*XSTR + tid];
      __syncthreads();
    }

    // ===== S1 <- S1 @ Ws^T + 4*b_s (M=1) =====
    {
      float acc[1][4];
      gemm_tile<1,1>(WsW, S1, rg, cg, acc);
      __syncthreads();
      if (rg == 0) {
        #pragma unroll
        for (int j = 0; j < 4; j++)
          S1[cg + 32*j] = acc[0][j] + biasS4[cg + 32*j];
      }
      __syncthreads();
    }

    // ===== Level 1 node: h1 = e + S1; accumulate into H1 =====
    {
      if (tid < 32) {
        const int tok = tokens[tokbase + 1 + c1];
        *(float4*)(Xb + 4*tid) = ((const float4*)(emb + (long)tok * ED))[tid];
      }
      float acc[1][4];
      gemm_tile<1,1>(WcW, Xb, rg, cg, acc);
      __syncthreads();
      if (rg == 0) {
        #pragma unroll
        for (int j = 0; j < 4; j++) {
          const int c = cg + 32*j;
          float h = acc[0][j] + biasC[c] + S1[c];
          pmax[j] = fmaxf(pmax[j], h);
          H1[c] += h;  // each c written by exactly one thread
        }
      }
      __syncthreads();
    }
  }

  // ===== Root: h0 = (Wc·e0 + b_c) + (Ws·H1 + 4*b_s) =====
  {
    if (tid < 32) {
      const int tok = tokens[tokbase];
      *(float4*)(Xb + 4*tid) = ((const float4*)(emb + (long)tok * ED))[tid];
    }
    float accE[1][4];
    gemm_tile<1,1>(WcW, Xb, rg, cg, accE);
    float accS[1][4];
    gemm_tile<1,1>(WsW, H1, rg, cg, accS);
    __syncthreads();
    if (rg == 0) {
      #pragma unroll
      for (int j = 0; j < 4; j++) {
        const int c = cg + 32*j;
        float h0 = accE[0][j] + biasC[c] + accS[0][j] + biasS4[c];
        pmax[j] = fmaxf(pmax[j], h0);
      }
    }
  }

  // ===== Block-level max reduce, plain store =====
  __syncthreads();
  #pragma unroll
  for (int j = 0; j < 4; j++) Xb[rg*XSTR + cg + 32*j] = pmax[j];
  __syncthreads();
  if (tid < 128) {
    float m = 0.f;
    #pragma unroll
    for (int r = 0; r < 16; r++) m = fmaxf(m, Xb[r*XSTR + tid]);
    out[(long)b*ED + tid] = m;
  }
}

extern "C" void kernel_launch(void* const* d_in, const int* in_sizes, int n_in,
                              void* d_out, int out_size, void* d_ws, size_t ws_size,
                              hipStream_t stream) {
  const int*   tokens = (const int*)d_in[0];
  const float* emb    = (const float*)d_in[1];
  const float* WcW    = (const float*)d_in[2];
  const float* Wcb    = (const float*)d_in[3];
  const float* WsW    = (const float*)d_in[4];
  const float* Wsb    = (const float*)d_in[5];
  float* out = (float*)d_out;
  (void)d_ws; (void)ws_size;  // unused: kernel is a pure function of d_in

  tree_kernel<<<512, 512, 0, stream>>>(tokens, emb, WcW, Wcb, WsW, Wsb, out);
}

// Round 3
// 185.247 us; speedup vs baseline: 6.1354x; 6.1354x over previous
//
#include <hip/hip_runtime.h>
#include <hip/hip_bf16.h>

// B=512, A=4, D=6, N=1365, E=128. Level starts {0,1,5,21,85,341}.
// One block per batch element, 512 thr (8 waves). Whole tree bottom-up in LDS.
// bf16 MFMA (16x16x32), fp32 accum. Pure function of d_in (no ws/atomics).
#define NTOK 1365
#define ED   128
#define STR  136   // bf16 row stride: 272 B, 16B-aligned; spreads frag reads over banks

typedef __attribute__((ext_vector_type(8))) short short8;
typedef __attribute__((ext_vector_type(4))) float f32x4;

#define MFMA(a,b,c) __builtin_amdgcn_mfma_f32_16x16x32_bf16((a),(b),(c),0,0,0)

__device__ __forceinline__ ushort f2bf(float f) {  // round-to-nearest-even
  union { float f; unsigned u; } v; v.f = f;
  unsigned r = v.u + 0x7fffu + ((v.u >> 16) & 1u);
  return (ushort)(r >> 16);
}

// LDS: PM 8*132 f + H1/biasC/biasS4 128 f each = 5760 B; then bf16:
// WcL 128*STR, WsL 128*STR, Xe 64*STR, CS4 64*STR, CSa 16*STR, CSb 16*STR
#define SM_BYTES (5760 + 2*(128*STR + 128*STR + 64*STR + 64*STR + 16*STR + 16*STR))

__global__ __launch_bounds__(512, 1) void tree_kernel(
    const int* __restrict__ tokens, const float* __restrict__ emb,
    const float* __restrict__ WcW,  const float* __restrict__ Wcb,
    const float* __restrict__ WsW,  const float* __restrict__ Wsb,
    float* __restrict__ out) {
  extern __shared__ char smem[];
  float*  PM  = (float*)smem;        // [8][132] per-wave col maxima
  float*  H1  = PM + 8*132;          // sum of 4 level-1 h (fp32)
  float*  bC  = H1 + 128;
  float*  bS4 = bC + 128;            // 4*Ws_b
  ushort* WcL = (ushort*)(bS4 + 128);
  ushort* WsL = WcL + 128*STR;
  ushort* Xe  = WsL + 128*STR;       // 64-row staging (embeddings, bf16)
  ushort* CS4 = Xe  + 64*STR;        // level-4 child-sums (64 rows / c1)
  ushort* CSa = CS4 + 64*STR;        // 16 rows
  ushort* CSb = CSa + 16*STR;        // 16 rows

  const int  tid = threadIdx.x;
  const int  b   = blockIdx.x;
  const long tokbase = (long)b * NTOK;
  const int  w    = tid >> 6;        // wave 0..7
  const int  lane = tid & 63;
  const int  n16  = lane & 15;       // A-row / B-col / C-col field
  const int  quad = lane >> 4;       // k-group for A/B; row-group for C
  const int  mtg  = w >> 2, ntg = w & 3;   // M=64 phases: 2x4 wave grid of 2x2 tiles
  const int  kof  = quad * 8;

  // ---- stage Wc, Ws as bf16 into LDS (once per block) ----
  #pragma unroll
  for (int i = 0; i < 8; i++) {
    int idx = tid + i*512;                       // float4 index over 4096
    float4 f = ((const float4*)WcW)[idx];
    ushort4 u; u.x=f2bf(f.x); u.y=f2bf(f.y); u.z=f2bf(f.z); u.w=f2bf(f.w);
    *(ushort4*)(WcL + (idx >> 5)*STR + ((idx & 31) << 2)) = u;
  }
  #pragma unroll
  for (int i = 0; i < 8; i++) {
    int idx = tid + i*512;
    float4 f = ((const float4*)WsW)[idx];
    ushort4 u; u.x=f2bf(f.x); u.y=f2bf(f.y); u.z=f2bf(f.z); u.w=f2bf(f.w);
    *(ushort4*)(WsL + (idx >> 5)*STR + ((idx & 31) << 2)) = u;
  }
  if (tid < 128) { bC[tid] = Wcb[tid]; bS4[tid] = 4.f*Wsb[tid]; H1[tid] = 0.f; }
  for (int i = tid; i < 8*132; i += 512) PM[i] = 0.f;
  __syncthreads();

  // hoisted per-lane biases
  float bcv[2], bsv[2];
  #pragma unroll
  for (int j = 0; j < 2; j++) {
    int c = ntg*32 + j*16 + n16;
    bcv[j] = bC[c]; bsv[j] = bS4[c];
  }
  const int   csm = w*16 + n16;                  // small-phase col
  const float bcs = bC[csm], bss = bS4[csm];

  float pm[2] = {0.f, 0.f};   // relu floor; M=64-phase cols ntg*32+j*16+n16
  float pms   = 0.f;          // small-phase col csm

  // ---- gathers: fp32 emb -> bf16 LDS rows ----
  auto gather64 = [&](int nodeofs) {             // 64 rows, 8 thr/row
    int r = tid >> 3, p = tid & 7;
    int tok = tokens[tokbase + nodeofs + r];
    const float4* src = (const float4*)(emb + (long)tok * ED) + (p << 2);
    float4 f0 = src[0], f1 = src[1], f2 = src[2], f3 = src[3];
    ushort4* d = (ushort4*)(Xe + r*STR + (p << 4));
    ushort4 u;
    u.x=f2bf(f0.x); u.y=f2bf(f0.y); u.z=f2bf(f0.z); u.w=f2bf(f0.w); d[0]=u;
    u.x=f2bf(f1.x); u.y=f2bf(f1.y); u.z=f2bf(f1.z); u.w=f2bf(f1.w); d[1]=u;
    u.x=f2bf(f2.x); u.y=f2bf(f2.y); u.z=f2bf(f2.z); u.w=f2bf(f2.w); d[2]=u;
    u.x=f2bf(f3.x); u.y=f2bf(f3.y); u.z=f2bf(f3.z); u.w=f2bf(f3.w); d[3]=u;
  };
  auto gatherN = [&](int nodeofs, int nrows) {   // nrows in {16,4,1}, 32 thr/row
    int r = tid >> 5, p = tid & 31;
    if (r < nrows) {
      int tok = tokens[tokbase + nodeofs + r];
      float4 f = ((const float4*)(emb + (long)tok * ED))[p];
      ushort4 u; u.x=f2bf(f.x); u.y=f2bf(f.y); u.z=f2bf(f.z); u.w=f2bf(f.w);
      *(ushort4*)(Xe + r*STR + (p << 2)) = u;
    }
  };

  // ---- M=64 phase: acc = Xe@WcL^T (+ CS4@WsL^T). Epilogue: h=acc+bias, pm,
  //      child-sums (4 children live in one lane's 4 C-regs) -> csdst ----
  auto phase64 = [&](bool chain2, ushort* csdst, int csrow0) {
    f32x4 acc[2][2];
    #pragma unroll
    for (int i = 0; i < 2; i++)
      #pragma unroll
      for (int j = 0; j < 2; j++) acc[i][j] = (f32x4){0.f,0.f,0.f,0.f};
    #pragma unroll
    for (int kb = 0; kb < 4; kb++) {
      const int ko = kb*32 + kof;
      short8 a0 = *(const short8*)(Xe  + (mtg*32      + n16)*STR + ko);
      short8 a1 = *(const short8*)(Xe  + (mtg*32 + 16 + n16)*STR + ko);
      short8 b0 = *(const short8*)(WcL + (ntg*32      + n16)*STR + ko);
      short8 b1 = *(const short8*)(WcL + (ntg*32 + 16 + n16)*STR + ko);
      acc[0][0]=MFMA(a0,b0,acc[0][0]); acc[0][1]=MFMA(a0,b1,acc[0][1]);
      acc[1][0]=MFMA(a1,b0,acc[1][0]); acc[1][1]=MFMA(a1,b1,acc[1][1]);
      if (chain2) {
        short8 c0 = *(const short8*)(CS4 + (mtg*32      + n16)*STR + ko);
        short8 c1 = *(const short8*)(CS4 + (mtg*32 + 16 + n16)*STR + ko);
        short8 d0 = *(const short8*)(WsL + (ntg*32      + n16)*STR + ko);
        short8 d1 = *(const short8*)(WsL + (ntg*32 + 16 + n16)*STR + ko);
        acc[0][0]=MFMA(c0,d0,acc[0][0]); acc[0][1]=MFMA(c0,d1,acc[0][1]);
        acc[1][0]=MFMA(c1,d0,acc[1][0]); acc[1][1]=MFMA(c1,d1,acc[1][1]);
      }
    }
    #pragma unroll
    for (int i = 0; i < 2; i++) {
      int p = mtg*8 + i*4 + quad;                // parent index within chunk
      #pragma unroll
      for (int j = 0; j < 2; j++) {
        float bb = chain2 ? (bcv[j] + bsv[j]) : bcv[j];
        f32x4 A = acc[i][j];
        float h0=A[0]+bb, h1=A[1]+bb, h2=A[2]+bb, h3=A[3]+bb;
        pm[j] = fmaxf(pm[j], fmaxf(fmaxf(h0,h1), fmaxf(h2,h3)));
        float cs = A[0]+A[1]+A[2]+A[3] + 4.f*bb;
        csdst[(csrow0 + p)*STR + ntg*32 + j*16 + n16] = f2bf(cs);
      }
    }
  };

  // ---- small phase (M<=16): one 16x16 tile/wave (nt=w), dual chain ----
  // mode: 16 = L3 (write 4 child-sum rows), 4 = L2 (write row 0),
  //        1 = L1 (H1 += h), 0 = root (pm only)
  auto smallphase = [&](const ushort* csrc, int mode, ushort* csdst) {
    f32x4 acc = (f32x4){0.f,0.f,0.f,0.f};
    #pragma unroll
    for (int kb = 0; kb < 4; kb++) {
      const int ko = kb*32 + kof;
      short8 a  = *(const short8*)(Xe   + n16*STR + ko);
      short8 bb = *(const short8*)(WcL  + csm*STR + ko);
      acc = MFMA(a, bb, acc);
      short8 a2 = *(const short8*)(csrc + n16*STR + ko);
      short8 b2 = *(const short8*)(WsL  + csm*STR + ko);
      acc = MFMA(a2, b2, acc);
    }
    const float bb = bcs + bss;
    if (mode == 16) {
      float h0=acc[0]+bb, h1=acc[1]+bb, h2=acc[2]+bb, h3=acc[3]+bb;
      pms = fmaxf(pms, fmaxf(fmaxf(h0,h1), fmaxf(h2,h3)));
      csdst[quad*STR + csm] = f2bf(acc[0]+acc[1]+acc[2]+acc[3] + 4.f*bb);
    } else if (mode == 4) {
      if (quad == 0) {                            // rows 0-3 valid only
        float h0=acc[0]+bb, h1=acc[1]+bb, h2=acc[2]+bb, h3=acc[3]+bb;
        pms = fmaxf(pms, fmaxf(fmaxf(h0,h1), fmaxf(h2,h3)));
        csdst[csm] = f2bf(acc[0]+acc[1]+acc[2]+acc[3] + 4.f*bb);
      }
    } else {                                      // mode 1 / 0: row 0 only
      if (quad == 0) {
        float h = acc[0] + bb;
        pms = fmaxf(pms, h);
        if (mode == 1) H1[csm] += h;              // unique writer per col
      }
    }
  };

  for (int c1 = 0; c1 < 4; c1++) {
    // Level 5 (leaves): 4 chunks of 64; h = Wc e + b_c; quad-sums -> CS4
    for (int ch = 0; ch < 4; ch++) {
      gather64(341 + c1*256 + ch*64);  __syncthreads();
      phase64(false, CS4, ch*16);      __syncthreads();
    }
    // Level 4: h = Wc e + Ws cs + biases; child-sums -> CSa (16 rows)
    gather64(85 + c1*64);              __syncthreads();
    phase64(true, CSa, 0);             __syncthreads();
    // Level 3 (M=16): -> CSb rows 0-3
    gatherN(21 + c1*16, 16);           __syncthreads();
    smallphase(CSa, 16, CSb);          __syncthreads();
    // Level 2 (M=4): -> CSa row 0
    gatherN(5 + c1*4, 4);              __syncthreads();
    smallphase(CSb, 4, CSa);           __syncthreads();
    // Level 1 (M=1): h1 -> H1 (fp32 accumulate)
    gatherN(1 + c1, 1);                __syncthreads();
    smallphase(CSa, 1, nullptr);       __syncthreads();
  }

  // Root: h0 = Wc e0 + Ws H1 + biases
  if (tid < 128) CSa[tid] = f2bf(H1[tid]);
  gatherN(0, 1);
  __syncthreads();
  smallphase(CSa, 0, nullptr);

  // ---- merge per-lane maxima into PM, then final per-col max ----
  #pragma unroll
  for (int j = 0; j < 2; j++) {
    float v = pm[j];
    v = fmaxf(v, __shfl_xor(v, 16, 64));
    v = fmaxf(v, __shfl_xor(v, 32, 64));
    if (quad == 0) {
      float* s = PM + w*132 + ntg*32 + j*16 + n16;
      *s = fmaxf(*s, v);
    }
  }
  {
    float v = pms;
    v = fmaxf(v, __shfl_xor(v, 16, 64));
    v = fmaxf(v, __shfl_xor(v, 32, 64));
    if (quad == 0) {
      float* s = PM + w*132 + csm;
      *s = fmaxf(*s, v);
    }
  }
  __syncthreads();
  if (tid < 128) {
    float m = 0.f;
    #pragma unroll
    for (int r = 0; r < 8; r++) m = fmaxf(m, PM[r*132 + tid]);
    out[(long)b*ED + tid] = m;
  }
}

extern "C" void kernel_launch(void* const* d_in, const int* in_sizes, int n_in,
                              void* d_out, int out_size, void* d_ws, size_t ws_size,
                              hipStream_t stream) {
  const int*   tokens = (const int*)d_in[0];
  const float* emb    = (const float*)d_in[1];
  const float* WcW    = (const float*)d_in[2];
  const float* Wcb    = (const float*)d_in[3];
  const float* WsW    = (const float*)d_in[4];
  const float* Wsb    = (const float*)d_in[5];
  float* out = (float*)d_out;
  (void)d_ws; (void)ws_size;

  // >64 KiB dynamic LDS needs the opt-in attribute (idempotent; host-side,
  // not a stream op -> graph-capture safe)
  hipFuncSetAttribute(reinterpret_cast<const void*>(tree_kernel),
                      hipFuncAttributeMaxDynamicSharedMemorySize, SM_BYTES);
  tree_kernel<<<512, 512, SM_BYTES, stream>>>(tokens, emb, WcW, Wcb, WsW, Wsb, out);
}

// Round 4
// 182.599 us; speedup vs baseline: 6.2244x; 1.0145x over previous
//
#include <hip/hip_runtime.h>
#include <hip/hip_bf16.h>

// B=512, A=4, D=6, N=1365, E=128. Level starts {0,1,5,21,85,341}.
// One block per batch element, 512 thr (8 waves). Whole tree bottom-up.
// bf16 MFMA 16x16x32, fp32 accum. W fragments live in VGPRs (no W in LDS);
// embedding gathers are software-pipelined one phase ahead through registers
// into a double-buffered LDS staging area. Pure function of d_in.
#define NTOK 1365
#define ED   128
#define STR  136   // bf16 LDS row stride: 272 B, 16B-aligned, <=2-way bank alias

typedef __attribute__((ext_vector_type(8))) short short8;
typedef __attribute__((ext_vector_type(4))) float f32x4;

#define MFMA(a,b,c) __builtin_amdgcn_mfma_f32_16x16x32_bf16((a),(b),(c),0,0,0)

__device__ __forceinline__ ushort f2bf(float f) {  // round-to-nearest-even
  union { float f; unsigned u; } v; v.f = f;
  unsigned r = v.u + 0x7fffu + ((v.u >> 16) & 1u);
  return (ushort)(r >> 16);
}
__device__ __forceinline__ ushort4 cvt4(float4 f) {
  ushort4 u; u.x = f2bf(f.x); u.y = f2bf(f.y); u.z = f2bf(f.z); u.w = f2bf(f.w);
  return u;
}
__device__ __forceinline__ short8 pack8(float4 a, float4 b) {
  union { ushort us[8]; short8 s8; } t;
  t.us[0]=f2bf(a.x); t.us[1]=f2bf(a.y); t.us[2]=f2bf(a.z); t.us[3]=f2bf(a.w);
  t.us[4]=f2bf(b.x); t.us[5]=f2bf(b.y); t.us[6]=f2bf(b.z); t.us[7]=f2bf(b.w);
  return t.s8;
}

// LDS: floats PM 8*132 + H1/bC/bS4 (1440 f = 5760 B), TOK 1376 ints (5504 B),
// bf16 rows: CS4 64 + CSa 16 + CSb 16 + Xe0 64 + Xe1 64 = 224*STR us (60928 B)
#define SM_BYTES (5760 + 5504 + 224 * STR * 2)

__global__ __launch_bounds__(512, 2) void tree_kernel(
    const int* __restrict__ tokens, const float* __restrict__ emb,
    const float* __restrict__ WcW,  const float* __restrict__ Wcb,
    const float* __restrict__ WsW,  const float* __restrict__ Wsb,
    float* __restrict__ out) {
  extern __shared__ char smem[];
  float*  PM  = (float*)smem;          // [8][132] per-wave col maxima
  float*  H1  = PM + 8*132;
  float*  bC  = H1 + 128;
  float*  bS4 = bC + 128;              // 4*Ws_b
  int*    TOK = (int*)(bS4 + 128);     // this block's 1365 tokens
  ushort* CS4 = (ushort*)(TOK + 1376); // level-4 child-sums (64 rows)
  ushort* CSa = CS4 + 64*STR;          // 16 rows
  ushort* CSb = CSa + 16*STR;          // 16 rows
  ushort* Xe0 = CSb + 16*STR;          // staging buf 0 (64 rows)
  ushort* Xe1 = Xe0 + 64*STR;          // staging buf 1

  const int  tid = threadIdx.x;
  const int  b   = blockIdx.x;
  const long tokbase = (long)b * NTOK;
  const int  w    = tid >> 6;          // wave 0..7
  const int  lane = tid & 63;
  const int  n16  = lane & 15;
  const int  quad = lane >> 4;
  const int  mtg  = w >> 2, ntg = w & 3;   // 2x4 wave grid for M=64 phases
  const int  kof  = quad * 8;
  const int  csm  = w*16 + n16;            // small-phase column

  // ---- resident B fragments (global -> VGPR, once per block) ----
  short8 Bc64[2][4], Bs64[2][4], BcS[4], BsS[4];
  #pragma unroll
  for (int jt = 0; jt < 2; jt++)
    #pragma unroll
    for (int kb = 0; kb < 4; kb++) {
      const float* pc = WcW + (ntg*32 + jt*16 + n16)*ED + kb*32 + kof;
      Bc64[jt][kb] = pack8(((const float4*)pc)[0], ((const float4*)pc)[1]);
      const float* ps = WsW + (ntg*32 + jt*16 + n16)*ED + kb*32 + kof;
      Bs64[jt][kb] = pack8(((const float4*)ps)[0], ((const float4*)ps)[1]);
    }
  #pragma unroll
  for (int kb = 0; kb < 4; kb++) {
    const float* pc = WcW + csm*ED + kb*32 + kof;
    BcS[kb] = pack8(((const float4*)pc)[0], ((const float4*)pc)[1]);
    const float* ps = WsW + csm*ED + kb*32 + kof;
    BsS[kb] = pack8(((const float4*)ps)[0], ((const float4*)ps)[1]);
  }

  // ---- stage tokens + init LDS state ----
  for (int i = tid; i < NTOK; i += 512) TOK[i] = tokens[tokbase + i];
  if (tid < 128) { bC[tid] = Wcb[tid]; bS4[tid] = 4.f*Wsb[tid]; H1[tid] = 0.f; }
  for (int i = tid; i < 8*132; i += 512) PM[i] = 0.f;
  __syncthreads();

  float bcv[2], bsv[2];
  #pragma unroll
  for (int j = 0; j < 2; j++) {
    bcv[j] = bC[ntg*32 + j*16 + n16];
    bsv[j] = bS4[ntg*32 + j*16 + n16];
  }
  const float bcs = bC[csm], bss = bS4[csm];

  float pm[2] = {0.f, 0.f};
  float pms   = 0.f;

  // ---- pipelined gather: issue into regs, store to LDS one phase later ----
  float4 R0, R1, R2, R3;
  auto issue64 = [&](int nodeofs) {          // 64 rows, 8 thr/row, 64B/thread
    const int r = tid >> 3, p = tid & 7;
    const float4* src = (const float4*)(emb + (long)TOK[nodeofs + r] * ED) + (p << 2);
    R0 = src[0]; R1 = src[1]; R2 = src[2]; R3 = src[3];
  };
  auto store64 = [&](ushort* Xe) {
    const int r = tid >> 3, p = tid & 7;
    ushort4* d = (ushort4*)(Xe + r*STR + (p << 4));
    d[0] = cvt4(R0); d[1] = cvt4(R1); d[2] = cvt4(R2); d[3] = cvt4(R3);
  };
  auto issueN = [&](int nodeofs, int nrows) { // nrows in {16,4,1}, 32 thr/row
    const int r = tid >> 5, p = tid & 31;
    if (r < nrows) R0 = ((const float4*)(emb + (long)TOK[nodeofs + r] * ED))[p];
  };
  auto storeN = [&](ushort* Xe, int nrows) {
    const int r = tid >> 5, p = tid & 31;
    if (r < nrows) *(ushort4*)(Xe + r*STR + (p << 2)) = cvt4(R0);
  };

  // ---- M=64 phase: acc = Xe@Wc^T (+ CS4@Ws^T); epilogue: pm + child-sums ----
  auto phase64 = [&](const ushort* Xe, bool chain2, ushort* csdst, int csrow0) {
    f32x4 acc[2][2];
    #pragma unroll
    for (int i = 0; i < 2; i++)
      #pragma unroll
      for (int j = 0; j < 2; j++) acc[i][j] = (f32x4){0.f,0.f,0.f,0.f};
    #pragma unroll
    for (int kb = 0; kb < 4; kb++) {
      const int ko = kb*32 + kof;
      short8 a0 = *(const short8*)(Xe + (mtg*32      + n16)*STR + ko);
      short8 a1 = *(const short8*)(Xe + (mtg*32 + 16 + n16)*STR + ko);
      acc[0][0]=MFMA(a0,Bc64[0][kb],acc[0][0]); acc[0][1]=MFMA(a0,Bc64[1][kb],acc[0][1]);
      acc[1][0]=MFMA(a1,Bc64[0][kb],acc[1][0]); acc[1][1]=MFMA(a1,Bc64[1][kb],acc[1][1]);
      if (chain2) {
        short8 c0 = *(const short8*)(CS4 + (mtg*32      + n16)*STR + ko);
        short8 c1 = *(const short8*)(CS4 + (mtg*32 + 16 + n16)*STR + ko);
        acc[0][0]=MFMA(c0,Bs64[0][kb],acc[0][0]); acc[0][1]=MFMA(c0,Bs64[1][kb],acc[0][1]);
        acc[1][0]=MFMA(c1,Bs64[0][kb],acc[1][0]); acc[1][1]=MFMA(c1,Bs64[1][kb],acc[1][1]);
      }
    }
    #pragma unroll
    for (int i = 0; i < 2; i++) {
      const int p = mtg*8 + i*4 + quad;       // parent index within 64-row chunk
      #pragma unroll
      for (int j = 0; j < 2; j++) {
        const float bb = chain2 ? (bcv[j] + bsv[j]) : bcv[j];
        f32x4 A = acc[i][j];
        float h0=A[0]+bb, h1=A[1]+bb, h2=A[2]+bb, h3=A[3]+bb;
        pm[j] = fmaxf(pm[j], fmaxf(fmaxf(h0,h1), fmaxf(h2,h3)));
        float cs = A[0]+A[1]+A[2]+A[3] + 4.f*bb;
        csdst[(csrow0 + p)*STR + ntg*32 + j*16 + n16] = f2bf(cs);
      }
    }
  };

  // ---- small phase (M<=16): one 16x16 tile/wave, dual chain ----
  // mode 16: write 4 child-sum rows; 4: write row 0; 1: H1 += h; 0: pm only
  auto smallphase = [&](const ushort* Xe, const ushort* csrc, int mode, ushort* csdst) {
    f32x4 acc = (f32x4){0.f,0.f,0.f,0.f};
    #pragma unroll
    for (int kb = 0; kb < 4; kb++) {
      const int ko = kb*32 + kof;
      short8 a  = *(const short8*)(Xe   + n16*STR + ko);
      acc = MFMA(a, BcS[kb], acc);
      short8 a2 = *(const short8*)(csrc + n16*STR + ko);
      acc = MFMA(a2, BsS[kb], acc);
    }
    const float bb = bcs + bss;
    if (mode == 16) {
      float h0=acc[0]+bb, h1=acc[1]+bb, h2=acc[2]+bb, h3=acc[3]+bb;
      pms = fmaxf(pms, fmaxf(fmaxf(h0,h1), fmaxf(h2,h3)));
      csdst[quad*STR + csm] = f2bf(acc[0]+acc[1]+acc[2]+acc[3] + 4.f*bb);
    } else if (mode == 4) {
      if (quad == 0) {
        float h0=acc[0]+bb, h1=acc[1]+bb, h2=acc[2]+bb, h3=acc[3]+bb;
        pms = fmaxf(pms, fmaxf(fmaxf(h0,h1), fmaxf(h2,h3)));
        csdst[csm] = f2bf(acc[0]+acc[1]+acc[2]+acc[3] + 4.f*bb);
      }
    } else {
      if (quad == 0) {
        float h = acc[0] + bb;
        pms = fmaxf(pms, h);
        if (mode == 1) H1[csm] += h;          // unique writer per column
      }
    }
  };

  // ---- pipeline driver: [store n | issue n+1 | sync | compute n] ----
  ushort* XB[2] = {Xe0, Xe1};
  int pb = 0;
  issue64(341);                                // c1=0, leaves chunk 0
  for (int c1 = 0; c1 < 4; c1++) {
    for (int ch = 0; ch < 4; ch++) {           // level 5: 4 chunks of 64
      ushort* xb = XB[pb]; pb ^= 1;
      store64(xb);
      if (ch < 3) issue64(341 + c1*256 + (ch+1)*64);
      else        issue64(85 + c1*64);
      __syncthreads();
      phase64(xb, false, CS4, ch*16);
    }
    { ushort* xb = XB[pb]; pb ^= 1;            // level 4 (dual chain)
      store64(xb);
      issueN(21 + c1*16, 16);
      __syncthreads();
      phase64(xb, true, CSa, 0);
    }
    { ushort* xb = XB[pb]; pb ^= 1;            // level 3 (M=16)
      storeN(xb, 16);
      issueN(5 + c1*4, 4);
      __syncthreads();
      smallphase(xb, CSa, 16, CSb);
    }
    { ushort* xb = XB[pb]; pb ^= 1;            // level 2 (M=4)
      storeN(xb, 4);
      issueN(1 + c1, 1);
      __syncthreads();
      smallphase(xb, CSb, 4, CSa);
    }
    { ushort* xb = XB[pb]; pb ^= 1;            // level 1 (M=1) -> H1
      storeN(xb, 1);
      if (c1 < 3) issue64(341 + (c1+1)*256);
      else        issueN(0, 1);
      __syncthreads();
      smallphase(xb, CSa, 1, nullptr);
    }
  }
  { ushort* xb = XB[pb]; pb ^= 1;              // root
    storeN(xb, 1);
    __syncthreads();                           // H1 complete & visible
    if (tid < 128) CSb[tid] = f2bf(H1[tid]);
    __syncthreads();
    smallphase(xb, CSb, 0, nullptr);
  }

  // ---- merge per-lane maxima -> PM -> out ----
  #pragma unroll
  for (int j = 0; j < 2; j++) {
    float v = pm[j];
    v = fmaxf(v, __shfl_xor(v, 16, 64));
    v = fmaxf(v, __shfl_xor(v, 32, 64));
    if (quad == 0) {
      float* s = PM + w*132 + ntg*32 + j*16 + n16;
      *s = fmaxf(*s, v);
    }
  }
  {
    float v = pms;
    v = fmaxf(v, __shfl_xor(v, 16, 64));
    v = fmaxf(v, __shfl_xor(v, 32, 64));
    if (quad == 0) {
      float* s = PM + w*132 + csm;
      *s = fmaxf(*s, v);
    }
  }
  __syncthreads();
  if (tid < 128) {
    float m = 0.f;
    #pragma unroll
    for (int r = 0; r < 8; r++) m = fmaxf(m, PM[r*132 + tid]);
    out[(long)b*ED + tid] = m;
  }
}

extern "C" void kernel_launch(void* const* d_in, const int* in_sizes, int n_in,
                              void* d_out, int out_size, void* d_ws, size_t ws_size,
                              hipStream_t stream) {
  const int*   tokens = (const int*)d_in[0];
  const float* emb    = (const float*)d_in[1];
  const float* WcW    = (const float*)d_in[2];
  const float* Wcb    = (const float*)d_in[3];
  const float* WsW    = (const float*)d_in[4];
  const float* Wsb    = (const float*)d_in[5];
  float* out = (float*)d_out;
  (void)d_ws; (void)ws_size;

  hipFuncSetAttribute(reinterpret_cast<const void*>(tree_kernel),
                      hipFuncAttributeMaxDynamicSharedMemorySize, SM_BYTES);
  tree_kernel<<<512, 512, SM_BYTES, stream>>>(tokens, emb, WcW, Wcb, WsW, Wsb, out);
}